// Round 7
// baseline (146.381 us; speedup 1.0000x reference)
//
#include <hip/hip_runtime.h>

#define BB 8
#define NN 512
#define SS 96
#define HH 256
#define NHD 8
#define HDD 32
#define OUTD 4

// bf16 weight region (ushort offsets from ws base)
#define WSB_OFF  0
#define WQB_OFF  65536
#define WAOB_OFF 131072
#define W1B_OFF  196608
#define WO1B_OFF 262144
#define CAST_TOTAL 294912
#define KB_OFF   294912                    // [768][256] bf16 k
#define VTB_OFF  491520                    // [B][256][96] bf16 v-transposed

typedef __attribute__((ext_vector_type(8))) short bf16x8;
typedef __attribute__((ext_vector_type(4))) float f32x4;

__device__ __forceinline__ unsigned short f2bf(float f) {
    unsigned int u = __float_as_uint(f);
    u = (u + 0x7FFFu + ((u >> 16) & 1u)) >> 16;   // RNE
    return (unsigned short)u;
}

// load 8 consecutive fp32 -> bf16x8 fragment (inline cvt)
__device__ __forceinline__ bf16x8 ldw8(const float* __restrict__ p) {
    float4 a = *(const float4*)p, b = *(const float4*)(p + 4);
    bf16x8 r;
    r[0] = (short)f2bf(a.x); r[1] = (short)f2bf(a.y);
    r[2] = (short)f2bf(a.z); r[3] = (short)f2bf(a.w);
    r[4] = (short)f2bf(b.x); r[5] = (short)f2bf(b.y);
    r[6] = (short)f2bf(b.z); r[7] = (short)f2bf(b.w);
    return r;
}

// ============================================================
// MFMA helpers (validated R4/R6). Block = 256 thr / 4 waves, 16-row A tile.
// A in LDS bf16 [16][256], 16B-slot XOR swizzle: slot' = slot ^ (row&7).
// W (bf16 variant): global [NC][256] row-major.
// ============================================================
template<int NCT>
__device__ __forceinline__ void mfma_stage(
    const unsigned short* __restrict__ Asw,
    const unsigned short* __restrict__ Wb,
    int lane, int wave, f32x4 acc[NCT])
{
    const int row = lane & 15, kq = lane >> 4;
    #pragma unroll
    for (int ct = 0; ct < NCT; ++ct) acc[ct] = (f32x4){0.f, 0.f, 0.f, 0.f};
    #pragma unroll 2
    for (int kt = 0; kt < 8; ++kt) {
        const int slot = kt * 4 + kq;
        bf16x8 a = *(const bf16x8*)(Asw + row * 256 + ((slot ^ (row & 7)) << 3));
        #pragma unroll
        for (int ct = 0; ct < NCT; ++ct) {
            const unsigned short* wp =
                Wb + (size_t)((wave * NCT + ct) * 16 + row) * 256 + kt * 32 + kq * 8;
            bf16x8 b = *(const bf16x8*)wp;
            acc[ct] = __builtin_amdgcn_mfma_f32_16x16x32_bf16(a, b, acc[ct], 0, 0, 0);
        }
    }
}

// same but W is fp32 global, converted inline (kernel A temporal path only)
template<int NCT>
__device__ __forceinline__ void mfma_stage_f32w(
    const unsigned short* __restrict__ Asw,
    const float* __restrict__ Wf,
    int lane, int wave, f32x4 acc[NCT])
{
    const int row = lane & 15, kq = lane >> 4;
    #pragma unroll
    for (int ct = 0; ct < NCT; ++ct) acc[ct] = (f32x4){0.f, 0.f, 0.f, 0.f};
    #pragma unroll 2
    for (int kt = 0; kt < 8; ++kt) {
        const int slot = kt * 4 + kq;
        bf16x8 a = *(const bf16x8*)(Asw + row * 256 + ((slot ^ (row & 7)) << 3));
        #pragma unroll
        for (int ct = 0; ct < NCT; ++ct) {
            const float* wp =
                Wf + (size_t)((wave * NCT + ct) * 16 + row) * 256 + kt * 32 + kq * 8;
            bf16x8 b = ldw8(wp);
            acc[ct] = __builtin_amdgcn_mfma_f32_16x16x32_bf16(a, b, acc[ct], 0, 0, 0);
        }
    }
}

template<int NCT, bool RELU>
__device__ __forceinline__ void epi_lds(
    unsigned short* __restrict__ OutSw, const float* __restrict__ bias,
    int lane, int wave, const f32x4 acc[NCT])
{
    const int col0 = lane & 15, rq = lane >> 4;
    #pragma unroll
    for (int ct = 0; ct < NCT; ++ct) {
        const int C = wave * NCT * 16 + ct * 16 + col0;
        const float bb = bias[C];
        const int slot = C >> 3, within = C & 7;
        #pragma unroll
        for (int r = 0; r < 4; ++r) {
            const int R = rq * 4 + r;
            float v = acc[ct][r] + bb;
            if (RELU) v = fmaxf(v, 0.f);
            OutSw[R * 256 + ((slot ^ (R & 7)) << 3) + within] = f2bf(v);
        }
    }
}

// epilogue -> global bf16 [16][256]
template<int NCT>
__device__ __forceinline__ void epi_gbf16(
    unsigned short* __restrict__ Og, const float* __restrict__ bias,
    int lane, int wave, const f32x4 acc[NCT])
{
    const int col0 = lane & 15, rq = lane >> 4;
    #pragma unroll
    for (int ct = 0; ct < NCT; ++ct) {
        const int C = wave * NCT * 16 + ct * 16 + col0;
        const float bb = bias[C];
        #pragma unroll
        for (int r = 0; r < 4; ++r) {
            const int R = rq * 4 + r;
            Og[(size_t)R * 256 + C] = f2bf(acc[ct][r] + bb);
        }
    }
}

// stage fp32 global [16][256] -> LDS bf16 swizzled
__device__ __forceinline__ void stage_A(
    const float* __restrict__ Ag, unsigned short* __restrict__ Asw, int tid)
{
    #pragma unroll
    for (int ii = 0; ii < 4; ++ii) {
        int i = tid + ii * 256;
        int row = i >> 6, c4 = i & 63;
        float4 v = ((const float4*)(Ag + (size_t)row * 256))[c4];
        int col = c4 * 4;
        int slot = col >> 3, half = (col >> 2) & 1;
        ushort4 o;
        o.x = f2bf(v.x); o.y = f2bf(v.y); o.z = f2bf(v.z); o.w = f2bf(v.w);
        *(ushort4*)(Asw + row * 256 + ((slot ^ (row & 7)) << 3) + half * 4) = o;
    }
}

// ---------------- Kernel A: temporal k/vT (fp32 weights inline) + weight cast ----------------
// blocks 0..47: temporal 16 rows -> k, vT ; blocks 48..95: cast Ws/Wq/Wao/W1/Wo1 -> bfw
__global__ __launch_bounds__(256) void k_prep(
    const float* __restrict__ temporal,
    const float* __restrict__ bt, const float* __restrict__ bin,
    const float* __restrict__ Wt, const float* __restrict__ Win,
    const float* __restrict__ Ws, const float* __restrict__ Wao,
    const float* __restrict__ W1, const float* __restrict__ Wo1,
    unsigned short* __restrict__ kb, unsigned short* __restrict__ vtb,
    unsigned short* __restrict__ bfw)
{
    const int tid = threadIdx.x;
    if (blockIdx.x < 48) {
        __shared__ __align__(16) unsigned short A0[16 * 256];
        __shared__ __align__(16) unsigned short MID[16 * 256];
        const int lane = tid & 63, wave = tid >> 6;
        const int r0 = blockIdx.x * 16;
        f32x4 acc[4];
        stage_A(temporal + (size_t)r0 * 256, A0, tid);
        __syncthreads();
        mfma_stage_f32w<4>(A0, Wt, lane, wave, acc);
        epi_lds<4, false>(MID, bt, lane, wave, acc);
        __syncthreads();
        mfma_stage_f32w<4>(MID, Win + 65536, lane, wave, acc);   // Wk
        epi_gbf16<4>(kb + (size_t)r0 * 256, bin + 256, lane, wave, acc);
        mfma_stage_f32w<4>(MID, Win + 131072, lane, wave, acc);  // Wv
        {   // vT epilogue: vtb[(b*256 + C)*96 + s]
            const int bb_ = r0 / 96, s0 = r0 % 96;
            const int col0 = lane & 15, rq = lane >> 4;
            #pragma unroll
            for (int ct = 0; ct < 4; ++ct) {
                const int C = wave * 64 + ct * 16 + col0;
                const float bv = bin[512 + C];
                #pragma unroll
                for (int r = 0; r < 4; ++r) {
                    const int R = rq * 4 + r;
                    vtb[((size_t)(bb_ * 256 + C)) * 96 + s0 + R] = f2bf(acc[ct][r] + bv);
                }
            }
        }
    } else {
        // cast: Ws | Win[0:65536] | Wao | W1 | Wo1 -> bfw (294912 elems, 6 iters)
        int idx = (blockIdx.x - 48) * 256 + tid;
        for (int j4 = idx; j4 < CAST_TOTAL / 4; j4 += 48 * 256) {
            int e = j4 * 4;
            const float* src; int off;
            if (e < 65536)       { src = Ws;  off = e; }
            else if (e < 131072) { src = Win; off = e - 65536; }
            else if (e < 196608) { src = Wao; off = e - 131072; }
            else if (e < 262144) { src = W1;  off = e - 196608; }
            else                 { src = Wo1; off = e - 262144; }
            float4 v = *(const float4*)(src + off);
            ushort4 o;
            o.x = f2bf(v.x); o.y = f2bf(v.y); o.z = f2bf(v.z); o.w = f2bf(v.w);
            *(ushort4*)(bfw + e) = o;
        }
    }
}

// ---------------- Kernel B: spatial -> q (LDS) -> attention -> head MLP -> broadcast ----------------
// grid B * N/16 = 256 blocks x 256 thr (4 waves). Wave w handles heads {2w, 2w+1}.
__global__ __launch_bounds__(256) void k_main(
    const float* __restrict__ spatial,
    const float* __restrict__ bs, const float* __restrict__ bin,
    const unsigned short* __restrict__ bfw,
    const unsigned short* __restrict__ kb, const unsigned short* __restrict__ vtb,
    const float* __restrict__ bao, const float* __restrict__ b1,
    const float* __restrict__ bo1,
    const float* __restrict__ Wo2, const float* __restrict__ bo2,
    float* __restrict__ out)
{
    __shared__ __align__(16) unsigned short A0[16 * 256];      // spatial-in, later ctx
    __shared__ __align__(16) unsigned short MID[16 * 256];
    __shared__ __align__(16) unsigned short Q[16 * 256];       // q, swizzled
    __shared__ __align__(16) unsigned short P[4][16 * 104];    // wave-private, pad 104
    __shared__ __align__(16) float H2[16 * 128];
    __shared__ __align__(16) float y[16][OUTD];
    const int tid = threadIdx.x, lane = tid & 63, wave = tid >> 6;
    const int b = blockIdx.x >> 5;
    const int n0 = (blockIdx.x & 31) * 16;
    const int cl = lane & 15, kq = lane >> 4;
    const float scale = 0.17677669529663687f;  // 1/sqrt(32)
    f32x4 acc[4];

    // ---- spatial projection chain: in -> sp -> q (all in LDS) ----
    stage_A(spatial + (size_t)(b * NN + n0) * 256, A0, tid);
    __syncthreads();
    mfma_stage<4>(A0, bfw + WSB_OFF, lane, wave, acc);
    epi_lds<4, false>(MID, bs, lane, wave, acc);
    __syncthreads();
    mfma_stage<4>(MID, bfw + WQB_OFF, lane, wave, acc);
    epi_lds<4, false>(Q, bin, lane, wave, acc);
    // wave w wrote Q cols [64w,64w+64) and reads heads 2w,2w+1 = same cols:
    // wave-private -> no barrier needed (in-order LDS within wave).

    // ---- attention: per wave 2 heads ----
    unsigned short* Pw = &P[wave][0];
    #pragma unroll
    for (int hh = 0; hh < 2; ++hh) {
        const int h = wave * 2 + hh;
        // q-frag from swizzled LDS: row=cl, cols h*32+kq*8 (slot = h*4+kq, within=0)
        const int slotq = h * 4 + kq;
        bf16x8 aq = *(const bf16x8*)(Q + cl * 256 + ((slotq ^ (cl & 7)) << 3));
        // QK^T: logits [16 n][96 s], 6 MFMA
        f32x4 l[6];
        #pragma unroll
        for (int t = 0; t < 6; ++t) {
            bf16x8 bk = *(const bf16x8*)(kb + (size_t)(b * SS + t * 16 + cl) * 256 + h * 32 + kq * 8);
            l[t] = __builtin_amdgcn_mfma_f32_16x16x32_bf16(aq, bk, (f32x4){0.f,0.f,0.f,0.f}, 0, 0, 0);
        }
        // softmax over s (D-layout: lane holds rows kq*4+r, col t*16+cl)
        float pr[6][4];
        float sum[4] = {0.f, 0.f, 0.f, 0.f};
        #pragma unroll
        for (int t = 0; t < 6; ++t)
            #pragma unroll
            for (int r = 0; r < 4; ++r) {
                float p = __expf(l[t][r] * scale);   // logits O(0.01): no max needed
                pr[t][r] = p; sum[r] += p;
            }
        #pragma unroll
        for (int r = 0; r < 4; ++r) {
            float s = sum[r];
            s += __shfl_xor(s, 1); s += __shfl_xor(s, 2);
            s += __shfl_xor(s, 4); s += __shfl_xor(s, 8);
            sum[r] = 1.0f / s;
        }
        // P -> bf16 -> wave-private LDS [16 n][104]
        #pragma unroll
        for (int t = 0; t < 6; ++t)
            #pragma unroll
            for (int r = 0; r < 4; ++r)
                Pw[(kq * 4 + r) * 104 + t * 16 + cl] = f2bf(pr[t][r] * sum[r]);
        // PV: ctx [16 n][32 d], 6 MFMA (A from P-lds, B from vT global)
        f32x4 c0 = (f32x4){0.f,0.f,0.f,0.f}, c1 = (f32x4){0.f,0.f,0.f,0.f};
        #pragma unroll
        for (int ks = 0; ks < 3; ++ks) {
            bf16x8 pa = *(const bf16x8*)(Pw + cl * 104 + ks * 32 + kq * 8);
            bf16x8 v0 = *(const bf16x8*)(vtb + (size_t)(b * 256 + h * 32 + cl) * 96 + ks * 32 + kq * 8);
            bf16x8 v1 = *(const bf16x8*)(vtb + (size_t)(b * 256 + h * 32 + 16 + cl) * 96 + ks * 32 + kq * 8);
            c0 = __builtin_amdgcn_mfma_f32_16x16x32_bf16(pa, v0, c0, 0, 0, 0);
            c1 = __builtin_amdgcn_mfma_f32_16x16x32_bf16(pa, v1, c1, 0, 0, 0);
        }
        // ctx -> A0 (bf16, swizzled), cols h*32 .. h*32+31
        #pragma unroll
        for (int dt = 0; dt < 2; ++dt) {
            const f32x4 cc = dt ? c1 : c0;
            const int C = h * 32 + dt * 16 + cl;
            const int slot = C >> 3, within = C & 7;
            #pragma unroll
            for (int r = 0; r < 4; ++r) {
                const int R = kq * 4 + r;
                A0[R * 256 + ((slot ^ (R & 7)) << 3) + within] = f2bf(cc[r]);
            }
        }
    }
    __syncthreads();

    // ---- head MLP (R4/R6-validated) ----
    mfma_stage<4>(A0, bfw + WAOB_OFF, lane, wave, acc);
    epi_lds<4, false>(MID, bao, lane, wave, acc);
    __syncthreads();
    mfma_stage<4>(MID, bfw + W1B_OFF, lane, wave, acc);
    epi_lds<4, true>(A0, b1, lane, wave, acc);
    __syncthreads();
    {
        f32x4 a2[2];
        mfma_stage<2>(A0, bfw + WO1B_OFF, lane, wave, a2);
        const int rq = lane >> 4;
        #pragma unroll
        for (int ct = 0; ct < 2; ++ct) {
            const int C = wave * 32 + ct * 16 + cl;
            const float bb = bo1[C];
            #pragma unroll
            for (int r = 0; r < 4; ++r) {
                const int R = rq * 4 + r;
                H2[R * 128 + C] = fmaxf(a2[ct][r] + bb, 0.f);
            }
        }
    }
    __syncthreads();
    if (tid < 64) {
        int r = tid >> 2, o = tid & 3;
        float a = 0.f;
        const float4* w4 = (const float4*)(Wo2 + (size_t)o * 128);
        const float4* h4 = (const float4*)(H2 + r * 128);
        for (int kk = 0; kk < 32; ++kk) {
            float4 w = w4[kk], hv = h4[kk];
            a += hv.x * w.x + hv.y * w.y + hv.z * w.z + hv.w * w.w;
        }
        y[r][o] = a + bo2[o];
    }
    __syncthreads();
    // broadcast: out[b][s][n0+r][:] = y[r]
    for (int i = tid; i < 16 * SS; i += 256) {
        int s = i >> 4;
        int r = i & 15;
        *(float4*)(out + ((size_t)(b * SS + s) * NN + (n0 + r)) * OUTD) = *(const float4*)y[r];
    }
}

extern "C" void kernel_launch(void* const* d_in, const int* in_sizes, int n_in,
                              void* d_out, int out_size, void* d_ws, size_t ws_size,
                              hipStream_t stream) {
    const float* spatial  = (const float*)d_in[0];
    const float* temporal = (const float*)d_in[1];
    const float* Ws  = (const float*)d_in[2];
    const float* bs  = (const float*)d_in[3];
    const float* Wt  = (const float*)d_in[4];
    const float* bt  = (const float*)d_in[5];
    const float* Win = (const float*)d_in[6];
    const float* bin = (const float*)d_in[7];
    const float* Wao = (const float*)d_in[8];
    const float* bao = (const float*)d_in[9];
    const float* W1  = (const float*)d_in[10];
    const float* b1  = (const float*)d_in[11];
    const float* Wo1 = (const float*)d_in[12];
    const float* bo1 = (const float*)d_in[13];
    const float* Wo2 = (const float*)d_in[14];
    const float* bo2 = (const float*)d_in[15];
    float* out = (float*)d_out;
    unsigned short* wsu = (unsigned short*)d_ws;

    unsigned short* bfw = wsu;
    unsigned short* kb  = wsu + KB_OFF;
    unsigned short* vtb = wsu + VTB_OFF;

    hipLaunchKernelGGL(k_prep, dim3(96), dim3(256), 0, stream,
                       temporal, bt, bin, Wt, Win, Ws, Wao, W1, Wo1,
                       kb, vtb, bfw);
    hipLaunchKernelGGL(k_main, dim3(256), dim3(256), 0, stream,
                       spatial, bs, bin, bfw, kb, vtb,
                       bao, b1, bo1, Wo2, bo2, out);
}

// Round 8
// 126.082 us; speedup vs baseline: 1.1610x; 1.1610x over previous
//
#include <hip/hip_runtime.h>

#define BB 8
#define NN 512
#define SS 96
#define HH 256
#define NHD 8
#define HDD 32
#define OUTD 4

// bf16 weight region (ushort offsets from ws base)
#define WSB_OFF  0
#define WQB_OFF  65536
#define WAOB_OFF 131072
#define W1B_OFF  196608
#define WO1B_OFF 262144
#define CAST_TOTAL 294912
#define KB_OFF   294912                    // [768][256] bf16 k
#define VTB_OFF  491520                    // [B][256][96] bf16 v-transposed

typedef __attribute__((ext_vector_type(8))) short bf16x8;
typedef __attribute__((ext_vector_type(4))) float f32x4;

__device__ __forceinline__ unsigned short f2bf(float f) {
    unsigned int u = __float_as_uint(f);
    u = (u + 0x7FFFu + ((u >> 16) & 1u)) >> 16;   // RNE
    return (unsigned short)u;
}

// load 8 consecutive fp32 -> bf16x8 fragment (inline cvt)
__device__ __forceinline__ bf16x8 ldw8(const float* __restrict__ p) {
    float4 a = *(const float4*)p, b = *(const float4*)(p + 4);
    bf16x8 r;
    r[0] = (short)f2bf(a.x); r[1] = (short)f2bf(a.y);
    r[2] = (short)f2bf(a.z); r[3] = (short)f2bf(a.w);
    r[4] = (short)f2bf(b.x); r[5] = (short)f2bf(b.y);
    r[6] = (short)f2bf(b.z); r[7] = (short)f2bf(b.w);
    return r;
}

// ============================================================
// MFMA helpers (validated R4/R6/R7). Block = 256 thr / 4 waves, 16-row A tile.
// A in LDS bf16 [16][256], 16B-slot XOR swizzle: slot' = slot ^ (row&7).
// ============================================================
template<int NCT>
__device__ __forceinline__ void mfma_stage(
    const unsigned short* __restrict__ Asw,
    const unsigned short* __restrict__ Wb,
    int lane, int wave, f32x4 acc[NCT])
{
    const int row = lane & 15, kq = lane >> 4;
    #pragma unroll
    for (int ct = 0; ct < NCT; ++ct) acc[ct] = (f32x4){0.f, 0.f, 0.f, 0.f};
    #pragma unroll 2
    for (int kt = 0; kt < 8; ++kt) {
        const int slot = kt * 4 + kq;
        bf16x8 a = *(const bf16x8*)(Asw + row * 256 + ((slot ^ (row & 7)) << 3));
        #pragma unroll
        for (int ct = 0; ct < NCT; ++ct) {
            const unsigned short* wp =
                Wb + (size_t)((wave * NCT + ct) * 16 + row) * 256 + kt * 32 + kq * 8;
            bf16x8 b = *(const bf16x8*)wp;
            acc[ct] = __builtin_amdgcn_mfma_f32_16x16x32_bf16(a, b, acc[ct], 0, 0, 0);
        }
    }
}

// same but W is fp32 global, converted inline (k_prep temporal path)
template<int NCT>
__device__ __forceinline__ void mfma_stage_f32w(
    const unsigned short* __restrict__ Asw,
    const float* __restrict__ Wf,
    int lane, int wave, f32x4 acc[NCT])
{
    const int row = lane & 15, kq = lane >> 4;
    #pragma unroll
    for (int ct = 0; ct < NCT; ++ct) acc[ct] = (f32x4){0.f, 0.f, 0.f, 0.f};
    #pragma unroll 2
    for (int kt = 0; kt < 8; ++kt) {
        const int slot = kt * 4 + kq;
        bf16x8 a = *(const bf16x8*)(Asw + row * 256 + ((slot ^ (row & 7)) << 3));
        #pragma unroll
        for (int ct = 0; ct < NCT; ++ct) {
            const float* wp =
                Wf + (size_t)((wave * NCT + ct) * 16 + row) * 256 + kt * 32 + kq * 8;
            bf16x8 b = ldw8(wp);
            acc[ct] = __builtin_amdgcn_mfma_f32_16x16x32_bf16(a, b, acc[ct], 0, 0, 0);
        }
    }
}

template<int NCT, bool RELU>
__device__ __forceinline__ void epi_lds(
    unsigned short* __restrict__ OutSw, const float* __restrict__ bias,
    int lane, int wave, const f32x4 acc[NCT])
{
    const int col0 = lane & 15, rq = lane >> 4;
    #pragma unroll
    for (int ct = 0; ct < NCT; ++ct) {
        const int C = wave * NCT * 16 + ct * 16 + col0;
        const float bb = bias[C];
        const int slot = C >> 3, within = C & 7;
        #pragma unroll
        for (int r = 0; r < 4; ++r) {
            const int R = rq * 4 + r;
            float v = acc[ct][r] + bb;
            if (RELU) v = fmaxf(v, 0.f);
            OutSw[R * 256 + ((slot ^ (R & 7)) << 3) + within] = f2bf(v);
        }
    }
}

// epilogue -> global bf16, row stride 256 (base may carry a column offset)
template<int NCT>
__device__ __forceinline__ void epi_gbf16(
    unsigned short* __restrict__ Og, const float* __restrict__ bias,
    int lane, int wave, const f32x4 acc[NCT])
{
    const int col0 = lane & 15, rq = lane >> 4;
    #pragma unroll
    for (int ct = 0; ct < NCT; ++ct) {
        const int C = wave * NCT * 16 + ct * 16 + col0;
        const float bb = bias[C];
        #pragma unroll
        for (int r = 0; r < 4; ++r) {
            const int R = rq * 4 + r;
            Og[(size_t)R * 256 + C] = f2bf(acc[ct][r] + bb);
        }
    }
}

// stage fp32 global [16][256] -> LDS bf16 swizzled
__device__ __forceinline__ void stage_A(
    const float* __restrict__ Ag, unsigned short* __restrict__ Asw, int tid)
{
    #pragma unroll
    for (int ii = 0; ii < 4; ++ii) {
        int i = tid + ii * 256;
        int row = i >> 6, c4 = i & 63;
        float4 v = ((const float4*)(Ag + (size_t)row * 256))[c4];
        int col = c4 * 4;
        int slot = col >> 3, half = (col >> 2) & 1;
        ushort4 o;
        o.x = f2bf(v.x); o.y = f2bf(v.y); o.z = f2bf(v.z); o.w = f2bf(v.w);
        *(ushort4*)(Asw + row * 256 + ((slot ^ (row & 7)) << 3) + half * 4) = o;
    }
}

// ---------------- Kernel A: temporal k/vT (col-split x4) + weight cast ----------------
// blocks 0..191: temporal, m = blk>>2 (16 rows), c = blk&3 (128-col slice of [k|v])
// blocks 192..239: cast Ws/Wq/Wao/W1/Wo1 -> bfw
__global__ __launch_bounds__(256) void k_prep(
    const float* __restrict__ temporal,
    const float* __restrict__ bt, const float* __restrict__ bin,
    const float* __restrict__ Wt, const float* __restrict__ Win,
    const float* __restrict__ Ws, const float* __restrict__ Wao,
    const float* __restrict__ W1, const float* __restrict__ Wo1,
    unsigned short* __restrict__ kb, unsigned short* __restrict__ vtb,
    unsigned short* __restrict__ bfw)
{
    const int tid = threadIdx.x;
    if (blockIdx.x < 192) {
        __shared__ __align__(16) unsigned short A0[16 * 256];
        __shared__ __align__(16) unsigned short MID[16 * 256];
        const int lane = tid & 63, wave = tid >> 6;
        const int m = blockIdx.x >> 2;
        const int c = blockIdx.x & 3;
        const int r0 = m * 16;
        f32x4 acc[4];
        stage_A(temporal + (size_t)r0 * 256, A0, tid);
        __syncthreads();
        mfma_stage_f32w<4>(A0, Wt, lane, wave, acc);           // tp (redundant x4, cheap)
        epi_lds<4, false>(MID, bt, lane, wave, acc);
        __syncthreads();
        f32x4 a2[2];
        if (c < 2) {
            // k slice: output cols [c*128, c*128+128)
            mfma_stage_f32w<2>(MID, Win + (size_t)(256 + c * 128) * 256, lane, wave, a2);
            epi_gbf16<2>(kb + (size_t)r0 * 256 + c * 128, bin + 256 + c * 128,
                         lane, wave, a2);
        } else {
            // v slice -> transposed store: v cols [(c-2)*128, ...+128)
            mfma_stage_f32w<2>(MID, Win + (size_t)(512 + (c - 2) * 128) * 256, lane, wave, a2);
            const int bb_ = r0 / 96, s0 = r0 % 96;
            const int col0 = lane & 15, rq = lane >> 4;
            #pragma unroll
            for (int ct = 0; ct < 2; ++ct) {
                const int Cl = (c - 2) * 128 + wave * 32 + ct * 16 + col0;
                const float bv = bin[512 + Cl];
                #pragma unroll
                for (int r = 0; r < 4; ++r) {
                    const int R = rq * 4 + r;
                    vtb[((size_t)(bb_ * 256 + Cl)) * 96 + s0 + R] = f2bf(a2[ct][r] + bv);
                }
            }
        }
    } else {
        // cast: Ws | Win[0:65536] | Wao | W1 | Wo1 -> bfw
        int idx = (blockIdx.x - 192) * 256 + tid;
        for (int j4 = idx; j4 < CAST_TOTAL / 4; j4 += 48 * 256) {
            int e = j4 * 4;
            const float* src; int off;
            if (e < 65536)       { src = Ws;  off = e; }
            else if (e < 131072) { src = Win; off = e - 65536; }
            else if (e < 196608) { src = Wao; off = e - 131072; }
            else if (e < 262144) { src = W1;  off = e - 196608; }
            else                 { src = Wo1; off = e - 262144; }
            float4 v = *(const float4*)(src + off);
            ushort4 o;
            o.x = f2bf(v.x); o.y = f2bf(v.y); o.z = f2bf(v.z); o.w = f2bf(v.w);
            *(ushort4*)(bfw + e) = o;
        }
    }
}

// ---------------- Kernel B: spatial -> q (LDS) -> attention -> head MLP -> broadcast ----------------
// grid B * N/16 = 256 blocks x 256 thr (4 waves). Wave w handles heads {2w, 2w+1}.
__global__ __launch_bounds__(256) void k_main(
    const float* __restrict__ spatial,
    const float* __restrict__ bs, const float* __restrict__ bin,
    const unsigned short* __restrict__ bfw,
    const unsigned short* __restrict__ kb, const unsigned short* __restrict__ vtb,
    const float* __restrict__ bao, const float* __restrict__ b1,
    const float* __restrict__ bo1,
    const float* __restrict__ Wo2, const float* __restrict__ bo2,
    float* __restrict__ out)
{
    __shared__ __align__(16) unsigned short A0[16 * 256];      // spatial-in, later ctx
    __shared__ __align__(16) unsigned short MID[16 * 256];
    __shared__ __align__(16) unsigned short Q[16 * 256];       // q, swizzled
    __shared__ __align__(16) unsigned short P[4][16 * 104];    // wave-private, pad 104
    __shared__ __align__(16) float H2[16 * 128];
    __shared__ __align__(16) float y[16][OUTD];
    const int tid = threadIdx.x, lane = tid & 63, wave = tid >> 6;
    const int b = blockIdx.x >> 5;
    const int n0 = (blockIdx.x & 31) * 16;
    const int cl = lane & 15, kq = lane >> 4;
    const float scale = 0.17677669529663687f;  // 1/sqrt(32)
    f32x4 acc[4];

    // ---- spatial projection chain: in -> sp -> q (all in LDS) ----
    stage_A(spatial + (size_t)(b * NN + n0) * 256, A0, tid);
    __syncthreads();
    mfma_stage<4>(A0, bfw + WSB_OFF, lane, wave, acc);
    epi_lds<4, false>(MID, bs, lane, wave, acc);
    __syncthreads();
    mfma_stage<4>(MID, bfw + WQB_OFF, lane, wave, acc);
    epi_lds<4, false>(Q, bin, lane, wave, acc);
    // wave w wrote Q cols [64w,64w+64) and reads heads 2w,2w+1 = same cols:
    // wave-private -> no barrier needed (in-wave LDS ordering).

    // ---- attention: per wave 2 heads ----
    unsigned short* Pw = &P[wave][0];
    #pragma unroll
    for (int hh = 0; hh < 2; ++hh) {
        const int h = wave * 2 + hh;
        // q-frag from swizzled LDS: row=cl, cols h*32+kq*8 (slot = h*4+kq)
        const int slotq = h * 4 + kq;
        bf16x8 aq = *(const bf16x8*)(Q + cl * 256 + ((slotq ^ (cl & 7)) << 3));
        // QK^T: logits [16 n][96 s], 6 MFMA
        f32x4 l[6];
        #pragma unroll
        for (int t = 0; t < 6; ++t) {
            bf16x8 bk = *(const bf16x8*)(kb + (size_t)(b * SS + t * 16 + cl) * 256 + h * 32 + kq * 8);
            l[t] = __builtin_amdgcn_mfma_f32_16x16x32_bf16(aq, bk, (f32x4){0.f,0.f,0.f,0.f}, 0, 0, 0);
        }
        // softmax over s (D-layout: lane holds rows kq*4+r, col t*16+cl)
        float pr[6][4];
        float sum[4] = {0.f, 0.f, 0.f, 0.f};
        #pragma unroll
        for (int t = 0; t < 6; ++t)
            #pragma unroll
            for (int r = 0; r < 4; ++r) {
                float p = __expf(l[t][r] * scale);   // logits O(0.01): no max needed
                pr[t][r] = p; sum[r] += p;
            }
        #pragma unroll
        for (int r = 0; r < 4; ++r) {
            float s = sum[r];
            s += __shfl_xor(s, 1); s += __shfl_xor(s, 2);
            s += __shfl_xor(s, 4); s += __shfl_xor(s, 8);
            sum[r] = 1.0f / s;
        }
        // P -> bf16 -> wave-private LDS [16 n][104]
        #pragma unroll
        for (int t = 0; t < 6; ++t)
            #pragma unroll
            for (int r = 0; r < 4; ++r)
                Pw[(kq * 4 + r) * 104 + t * 16 + cl] = f2bf(pr[t][r] * sum[r]);
        // PV: ctx [16 n][32 d], 6 MFMA (A from P-lds, B from vT global)
        f32x4 c0 = (f32x4){0.f,0.f,0.f,0.f}, c1 = (f32x4){0.f,0.f,0.f,0.f};
        #pragma unroll
        for (int ks = 0; ks < 3; ++ks) {
            bf16x8 pa = *(const bf16x8*)(Pw + cl * 104 + ks * 32 + kq * 8);
            bf16x8 v0 = *(const bf16x8*)(vtb + (size_t)(b * 256 + h * 32 + cl) * 96 + ks * 32 + kq * 8);
            bf16x8 v1 = *(const bf16x8*)(vtb + (size_t)(b * 256 + h * 32 + 16 + cl) * 96 + ks * 32 + kq * 8);
            c0 = __builtin_amdgcn_mfma_f32_16x16x32_bf16(pa, v0, c0, 0, 0, 0);
            c1 = __builtin_amdgcn_mfma_f32_16x16x32_bf16(pa, v1, c1, 0, 0, 0);
        }
        // ctx -> A0 (bf16, swizzled), cols h*32 .. h*32+31
        #pragma unroll
        for (int dt = 0; dt < 2; ++dt) {
            const f32x4 cc = dt ? c1 : c0;
            const int C = h * 32 + dt * 16 + cl;
            const int slot = C >> 3, within = C & 7;
            #pragma unroll
            for (int r = 0; r < 4; ++r) {
                const int R = kq * 4 + r;
                A0[R * 256 + ((slot ^ (R & 7)) << 3) + within] = f2bf(cc[r]);
            }
        }
    }
    __syncthreads();

    // ---- head MLP (R4/R6-validated) ----
    mfma_stage<4>(A0, bfw + WAOB_OFF, lane, wave, acc);
    epi_lds<4, false>(MID, bao, lane, wave, acc);
    __syncthreads();
    mfma_stage<4>(MID, bfw + W1B_OFF, lane, wave, acc);
    epi_lds<4, true>(A0, b1, lane, wave, acc);
    __syncthreads();
    {
        f32x4 a2[2];
        mfma_stage<2>(A0, bfw + WO1B_OFF, lane, wave, a2);
        const int rq = lane >> 4;
        #pragma unroll
        for (int ct = 0; ct < 2; ++ct) {
            const int C = wave * 32 + ct * 16 + cl;
            const float bb = bo1[C];
            #pragma unroll
            for (int r = 0; r < 4; ++r) {
                const int R = rq * 4 + r;
                H2[R * 128 + C] = fmaxf(a2[ct][r] + bb, 0.f);
            }
        }
    }
    __syncthreads();
    if (tid < 64) {
        int r = tid >> 2, o = tid & 3;
        float a = 0.f;
        const float4* w4 = (const float4*)(Wo2 + (size_t)o * 128);
        const float4* h4 = (const float4*)(H2 + r * 128);
        for (int kk = 0; kk < 32; ++kk) {
            float4 w = w4[kk], hv = h4[kk];
            a += hv.x * w.x + hv.y * w.y + hv.z * w.z + hv.w * w.w;
        }
        y[r][o] = a + bo2[o];
    }
    __syncthreads();
    // broadcast: out[b][s][n0+r][:] = y[r]
    for (int i = tid; i < 16 * SS; i += 256) {
        int s = i >> 4;
        int r = i & 15;
        *(float4*)(out + ((size_t)(b * SS + s) * NN + (n0 + r)) * OUTD) = *(const float4*)y[r];
    }
}

extern "C" void kernel_launch(void* const* d_in, const int* in_sizes, int n_in,
                              void* d_out, int out_size, void* d_ws, size_t ws_size,
                              hipStream_t stream) {
    const float* spatial  = (const float*)d_in[0];
    const float* temporal = (const float*)d_in[1];
    const float* Ws  = (const float*)d_in[2];
    const float* bs  = (const float*)d_in[3];
    const float* Wt  = (const float*)d_in[4];
    const float* bt  = (const float*)d_in[5];
    const float* Win = (const float*)d_in[6];
    const float* bin = (const float*)d_in[7];
    const float* Wao = (const float*)d_in[8];
    const float* bao = (const float*)d_in[9];
    const float* W1  = (const float*)d_in[10];
    const float* b1  = (const float*)d_in[11];
    const float* Wo1 = (const float*)d_in[12];
    const float* bo1 = (const float*)d_in[13];
    const float* Wo2 = (const float*)d_in[14];
    const float* bo2 = (const float*)d_in[15];
    float* out = (float*)d_out;
    unsigned short* wsu = (unsigned short*)d_ws;

    unsigned short* bfw = wsu;
    unsigned short* kb  = wsu + KB_OFF;
    unsigned short* vtb = wsu + VTB_OFF;

    hipLaunchKernelGGL(k_prep, dim3(240), dim3(256), 0, stream,
                       temporal, bt, bin, Wt, Win, Ws, Wao, W1, Wo1,
                       kb, vtb, bfw);
    hipLaunchKernelGGL(k_main, dim3(256), dim3(256), 0, stream,
                       spatial, bs, bin, bfw, kb, vtb,
                       bao, b1, bo1, Wo2, bo2, out);
}

// Round 9
// 123.340 us; speedup vs baseline: 1.1868x; 1.0222x over previous
//
#include <hip/hip_runtime.h>

#define BB 8
#define NN 512
#define SS 96
#define HH 256
#define NHD 8
#define HDD 32
#define OUTD 4

// bf16 weight region (ushort offsets from ws base)
#define WSB_OFF  0
#define WQB_OFF  65536
#define WAOB_OFF 131072
#define W1B_OFF  196608
#define WO1B_OFF 262144
#define CAST_TOTAL 294912
#define KB_OFF   294912                    // [768][256] bf16 k
#define VTB_OFF  491520                    // [B][256][96] bf16 v-transposed

typedef __attribute__((ext_vector_type(8))) short bf16x8;
typedef __attribute__((ext_vector_type(4))) float f32x4;

__device__ __forceinline__ unsigned short f2bf(float f) {
    unsigned int u = __float_as_uint(f);
    u = (u + 0x7FFFu + ((u >> 16) & 1u)) >> 16;   // RNE
    return (unsigned short)u;
}

// load 8 consecutive fp32 -> bf16x8 fragment (inline cvt)
__device__ __forceinline__ bf16x8 ldw8(const float* __restrict__ p) {
    float4 a = *(const float4*)p, b = *(const float4*)(p + 4);
    bf16x8 r;
    r[0] = (short)f2bf(a.x); r[1] = (short)f2bf(a.y);
    r[2] = (short)f2bf(a.z); r[3] = (short)f2bf(a.w);
    r[4] = (short)f2bf(b.x); r[5] = (short)f2bf(b.y);
    r[6] = (short)f2bf(b.z); r[7] = (short)f2bf(b.w);
    return r;
}

// ============================================================
// MFMA helpers (validated R4-R8). 16-row A tile in LDS bf16 [16][256],
// 16B-slot XOR swizzle: slot' = slot ^ (row&7).
// Wave w owns output cols [w*NCT*16, (w+1)*NCT*16) -> works for any wave count.
// ============================================================
template<int NCT>
__device__ __forceinline__ void mfma_stage(
    const unsigned short* __restrict__ Asw,
    const unsigned short* __restrict__ Wb,
    int lane, int wave, f32x4 acc[NCT])
{
    const int row = lane & 15, kq = lane >> 4;
    #pragma unroll
    for (int ct = 0; ct < NCT; ++ct) acc[ct] = (f32x4){0.f, 0.f, 0.f, 0.f};
    #pragma unroll 2
    for (int kt = 0; kt < 8; ++kt) {
        const int slot = kt * 4 + kq;
        bf16x8 a = *(const bf16x8*)(Asw + row * 256 + ((slot ^ (row & 7)) << 3));
        #pragma unroll
        for (int ct = 0; ct < NCT; ++ct) {
            const unsigned short* wp =
                Wb + (size_t)((wave * NCT + ct) * 16 + row) * 256 + kt * 32 + kq * 8;
            bf16x8 b = *(const bf16x8*)wp;
            acc[ct] = __builtin_amdgcn_mfma_f32_16x16x32_bf16(a, b, acc[ct], 0, 0, 0);
        }
    }
}

// same but W is fp32 global, converted inline (k_prep temporal path)
template<int NCT>
__device__ __forceinline__ void mfma_stage_f32w(
    const unsigned short* __restrict__ Asw,
    const float* __restrict__ Wf,
    int lane, int wave, f32x4 acc[NCT])
{
    const int row = lane & 15, kq = lane >> 4;
    #pragma unroll
    for (int ct = 0; ct < NCT; ++ct) acc[ct] = (f32x4){0.f, 0.f, 0.f, 0.f};
    #pragma unroll 2
    for (int kt = 0; kt < 8; ++kt) {
        const int slot = kt * 4 + kq;
        bf16x8 a = *(const bf16x8*)(Asw + row * 256 + ((slot ^ (row & 7)) << 3));
        #pragma unroll
        for (int ct = 0; ct < NCT; ++ct) {
            const float* wp =
                Wf + (size_t)((wave * NCT + ct) * 16 + row) * 256 + kt * 32 + kq * 8;
            bf16x8 b = ldw8(wp);
            acc[ct] = __builtin_amdgcn_mfma_f32_16x16x32_bf16(a, b, acc[ct], 0, 0, 0);
        }
    }
}

template<int NCT, bool RELU>
__device__ __forceinline__ void epi_lds(
    unsigned short* __restrict__ OutSw, const float* __restrict__ bias,
    int lane, int wave, const f32x4 acc[NCT])
{
    const int col0 = lane & 15, rq = lane >> 4;
    #pragma unroll
    for (int ct = 0; ct < NCT; ++ct) {
        const int C = wave * NCT * 16 + ct * 16 + col0;
        const float bb = bias[C];
        const int slot = C >> 3, within = C & 7;
        #pragma unroll
        for (int r = 0; r < 4; ++r) {
            const int R = rq * 4 + r;
            float v = acc[ct][r] + bb;
            if (RELU) v = fmaxf(v, 0.f);
            OutSw[R * 256 + ((slot ^ (R & 7)) << 3) + within] = f2bf(v);
        }
    }
}

// epilogue -> global bf16, row stride 256 (base may carry a column offset)
template<int NCT>
__device__ __forceinline__ void epi_gbf16(
    unsigned short* __restrict__ Og, const float* __restrict__ bias,
    int lane, int wave, const f32x4 acc[NCT])
{
    const int col0 = lane & 15, rq = lane >> 4;
    #pragma unroll
    for (int ct = 0; ct < NCT; ++ct) {
        const int C = wave * NCT * 16 + ct * 16 + col0;
        const float bb = bias[C];
        #pragma unroll
        for (int r = 0; r < 4; ++r) {
            const int R = rq * 4 + r;
            Og[(size_t)R * 256 + C] = f2bf(acc[ct][r] + bb);
        }
    }
}

// stage fp32 global [16][256] -> LDS bf16 swizzled (any block size >= 256)
template<int NT>
__device__ __forceinline__ void stage_A(
    const float* __restrict__ Ag, unsigned short* __restrict__ Asw, int tid)
{
    #pragma unroll
    for (int ii = 0; ii < 1024 / NT; ++ii) {
        int i = tid + ii * NT;
        int row = i >> 6, c4 = i & 63;
        float4 v = ((const float4*)(Ag + (size_t)row * 256))[c4];
        int col = c4 * 4;
        int slot = col >> 3, half = (col >> 2) & 1;
        ushort4 o;
        o.x = f2bf(v.x); o.y = f2bf(v.y); o.z = f2bf(v.z); o.w = f2bf(v.w);
        *(ushort4*)(Asw + row * 256 + ((slot ^ (row & 7)) << 3) + half * 4) = o;
    }
}

// ---------------- Kernel A: temporal k/vT (col-split x4) + weight cast ----------------
// 512 threads / 8 waves.
// blocks 0..191: temporal, m = blk>>2 (16 rows), c = blk&3 (128-col slice of [k|v])
// blocks 192..215: cast Ws/Wq/Wao/W1/Wo1 -> bfw
__global__ __launch_bounds__(512) void k_prep(
    const float* __restrict__ temporal,
    const float* __restrict__ bt, const float* __restrict__ bin,
    const float* __restrict__ Wt, const float* __restrict__ Win,
    const float* __restrict__ Ws, const float* __restrict__ Wao,
    const float* __restrict__ W1, const float* __restrict__ Wo1,
    unsigned short* __restrict__ kb, unsigned short* __restrict__ vtb,
    unsigned short* __restrict__ bfw)
{
    const int tid = threadIdx.x;
    if (blockIdx.x < 192) {
        __shared__ __align__(16) unsigned short A0[16 * 256];
        __shared__ __align__(16) unsigned short MID[16 * 256];
        const int lane = tid & 63, wave = tid >> 6;
        const int m = blockIdx.x >> 2;
        const int c = blockIdx.x & 3;
        const int r0 = m * 16;
        f32x4 acc[2];
        stage_A<512>(temporal + (size_t)r0 * 256, A0, tid);
        __syncthreads();
        mfma_stage_f32w<2>(A0, Wt, lane, wave, acc);           // tp (redundant x4, cheap)
        epi_lds<2, false>(MID, bt, lane, wave, acc);
        __syncthreads();
        f32x4 a1[1];
        if (c < 2) {
            // k slice: output cols [c*128, c*128+128)
            mfma_stage_f32w<1>(MID, Win + (size_t)(256 + c * 128) * 256, lane, wave, a1);
            epi_gbf16<1>(kb + (size_t)r0 * 256 + c * 128, bin + 256 + c * 128,
                         lane, wave, a1);
        } else {
            // v slice -> transposed store: v cols [(c-2)*128, ...+128)
            mfma_stage_f32w<1>(MID, Win + (size_t)(512 + (c - 2) * 128) * 256, lane, wave, a1);
            const int bb_ = r0 / 96, s0 = r0 % 96;
            const int col0 = lane & 15, rq = lane >> 4;
            const int Cl = (c - 2) * 128 + wave * 16 + col0;
            const float bv = bin[512 + Cl];
            #pragma unroll
            for (int r = 0; r < 4; ++r) {
                const int R = rq * 4 + r;
                vtb[((size_t)(bb_ * 256 + Cl)) * 96 + s0 + R] = f2bf(a1[0][r] + bv);
            }
        }
    } else {
        // cast: Ws | Win[0:65536] | Wao | W1 | Wo1 -> bfw
        int idx = (blockIdx.x - 192) * 512 + tid;
        for (int j4 = idx; j4 < CAST_TOTAL / 4; j4 += 24 * 512) {
            int e = j4 * 4;
            const float* src; int off;
            if (e < 65536)       { src = Ws;  off = e; }
            else if (e < 131072) { src = Win; off = e - 65536; }
            else if (e < 196608) { src = Wao; off = e - 131072; }
            else if (e < 262144) { src = W1;  off = e - 196608; }
            else                 { src = Wo1; off = e - 262144; }
            float4 v = *(const float4*)(src + off);
            ushort4 o;
            o.x = f2bf(v.x); o.y = f2bf(v.y); o.z = f2bf(v.z); o.w = f2bf(v.w);
            *(ushort4*)(bfw + e) = o;
        }
    }
}

// ---------------- Kernel B: spatial -> q (LDS) -> attention -> head MLP -> broadcast ----------------
// grid B * N/16 = 256 blocks x 512 thr (8 waves). Wave w: cols [32w,32w+32), head w.
__global__ __launch_bounds__(512) void k_main(
    const float* __restrict__ spatial,
    const float* __restrict__ bs, const float* __restrict__ bin,
    const unsigned short* __restrict__ bfw,
    const unsigned short* __restrict__ kb, const unsigned short* __restrict__ vtb,
    const float* __restrict__ bao, const float* __restrict__ b1,
    const float* __restrict__ bo1,
    const float* __restrict__ Wo2, const float* __restrict__ bo2,
    float* __restrict__ out)
{
    __shared__ __align__(16) unsigned short A0[16 * 256];      // spatial-in, later ctx
    __shared__ __align__(16) unsigned short MID[16 * 256];
    __shared__ __align__(16) unsigned short Q[16 * 256];       // q, swizzled
    __shared__ __align__(16) unsigned short P[8][16 * 104];    // wave-private, pad 104
    __shared__ __align__(16) float H2[16 * 128];
    __shared__ __align__(16) float y[16][OUTD];
    const int tid = threadIdx.x, lane = tid & 63, wave = tid >> 6;
    const int b = blockIdx.x >> 5;
    const int n0 = (blockIdx.x & 31) * 16;
    const int cl = lane & 15, kq = lane >> 4;
    const float scale = 0.17677669529663687f;  // 1/sqrt(32)
    f32x4 acc[2];

    // ---- spatial projection chain: in -> sp -> q (all in LDS) ----
    stage_A<512>(spatial + (size_t)(b * NN + n0) * 256, A0, tid);
    __syncthreads();
    mfma_stage<2>(A0, bfw + WSB_OFF, lane, wave, acc);
    epi_lds<2, false>(MID, bs, lane, wave, acc);
    __syncthreads();
    mfma_stage<2>(MID, bfw + WQB_OFF, lane, wave, acc);
    epi_lds<2, false>(Q, bin, lane, wave, acc);
    // wave w wrote Q cols [32w,32w+32) and reads head h=w = same cols:
    // wave-private -> no barrier needed (in-wave LDS ordering).

    // ---- attention: 1 head per wave ----
    unsigned short* Pw = &P[wave][0];
    {
        const int h = wave;
        // q-frag from swizzled LDS: row=cl, cols h*32+kq*8 (slot = h*4+kq)
        const int slotq = h * 4 + kq;
        bf16x8 aq = *(const bf16x8*)(Q + cl * 256 + ((slotq ^ (cl & 7)) << 3));
        // QK^T: logits [16 n][96 s], 6 MFMA
        f32x4 l[6];
        #pragma unroll
        for (int t = 0; t < 6; ++t) {
            bf16x8 bk = *(const bf16x8*)(kb + (size_t)(b * SS + t * 16 + cl) * 256 + h * 32 + kq * 8);
            l[t] = __builtin_amdgcn_mfma_f32_16x16x32_bf16(aq, bk, (f32x4){0.f,0.f,0.f,0.f}, 0, 0, 0);
        }
        // softmax over s (D-layout: lane holds rows kq*4+r, col t*16+cl)
        float pr[6][4];
        float sum[4] = {0.f, 0.f, 0.f, 0.f};
        #pragma unroll
        for (int t = 0; t < 6; ++t)
            #pragma unroll
            for (int r = 0; r < 4; ++r) {
                float p = __expf(l[t][r] * scale);   // logits O(0.01): no max needed
                pr[t][r] = p; sum[r] += p;
            }
        #pragma unroll
        for (int r = 0; r < 4; ++r) {
            float s = sum[r];
            s += __shfl_xor(s, 1); s += __shfl_xor(s, 2);
            s += __shfl_xor(s, 4); s += __shfl_xor(s, 8);
            sum[r] = 1.0f / s;
        }
        // P -> bf16 -> wave-private LDS [16 n][104]
        #pragma unroll
        for (int t = 0; t < 6; ++t)
            #pragma unroll
            for (int r = 0; r < 4; ++r)
                Pw[(kq * 4 + r) * 104 + t * 16 + cl] = f2bf(pr[t][r] * sum[r]);
        // PV: ctx [16 n][32 d], 6 MFMA (A from P-lds, B from vT global)
        f32x4 c0 = (f32x4){0.f,0.f,0.f,0.f}, c1 = (f32x4){0.f,0.f,0.f,0.f};
        #pragma unroll
        for (int ks = 0; ks < 3; ++ks) {
            bf16x8 pa = *(const bf16x8*)(Pw + cl * 104 + ks * 32 + kq * 8);
            bf16x8 v0 = *(const bf16x8*)(vtb + (size_t)(b * 256 + h * 32 + cl) * 96 + ks * 32 + kq * 8);
            bf16x8 v1 = *(const bf16x8*)(vtb + (size_t)(b * 256 + h * 32 + 16 + cl) * 96 + ks * 32 + kq * 8);
            c0 = __builtin_amdgcn_mfma_f32_16x16x32_bf16(pa, v0, c0, 0, 0, 0);
            c1 = __builtin_amdgcn_mfma_f32_16x16x32_bf16(pa, v1, c1, 0, 0, 0);
        }
        // ctx -> A0 (bf16, swizzled), cols h*32 .. h*32+31
        #pragma unroll
        for (int dt = 0; dt < 2; ++dt) {
            const f32x4 cc = dt ? c1 : c0;
            const int C = h * 32 + dt * 16 + cl;
            const int slot = C >> 3, within = C & 7;
            #pragma unroll
            for (int r = 0; r < 4; ++r) {
                const int R = kq * 4 + r;
                A0[R * 256 + ((slot ^ (R & 7)) << 3) + within] = f2bf(cc[r]);
            }
        }
    }
    __syncthreads();

    // ---- head MLP ----
    mfma_stage<2>(A0, bfw + WAOB_OFF, lane, wave, acc);
    epi_lds<2, false>(MID, bao, lane, wave, acc);
    __syncthreads();
    mfma_stage<2>(MID, bfw + W1B_OFF, lane, wave, acc);
    epi_lds<2, true>(A0, b1, lane, wave, acc);
    __syncthreads();
    {
        f32x4 a1[1];
        mfma_stage<1>(A0, bfw + WO1B_OFF, lane, wave, a1);
        const int rq = lane >> 4;
        const int C = wave * 16 + cl;
        const float bb = bo1[C];
        #pragma unroll
        for (int r = 0; r < 4; ++r) {
            const int R = rq * 4 + r;
            H2[R * 128 + C] = fmaxf(a1[0][r] + bb, 0.f);
        }
    }
    __syncthreads();
    if (tid < 64) {
        int r = tid >> 2, o = tid & 3;
        float a = 0.f;
        const float4* w4 = (const float4*)(Wo2 + (size_t)o * 128);
        const float4* h4 = (const float4*)(H2 + r * 128);
        for (int kk = 0; kk < 32; ++kk) {
            float4 w = w4[kk], hv = h4[kk];
            a += hv.x * w.x + hv.y * w.y + hv.z * w.z + hv.w * w.w;
        }
        y[r][o] = a + bo2[o];
    }
    __syncthreads();
    // broadcast: out[b][s][n0+r][:] = y[r]
    for (int i = tid; i < 16 * SS; i += 512) {
        int s = i >> 4;
        int r = i & 15;
        *(float4*)(out + ((size_t)(b * SS + s) * NN + (n0 + r)) * OUTD) = *(const float4*)y[r];
    }
}

extern "C" void kernel_launch(void* const* d_in, const int* in_sizes, int n_in,
                              void* d_out, int out_size, void* d_ws, size_t ws_size,
                              hipStream_t stream) {
    const float* spatial  = (const float*)d_in[0];
    const float* temporal = (const float*)d_in[1];
    const float* Ws  = (const float*)d_in[2];
    const float* bs  = (const float*)d_in[3];
    const float* Wt  = (const float*)d_in[4];
    const float* bt  = (const float*)d_in[5];
    const float* Win = (const float*)d_in[6];
    const float* bin = (const float*)d_in[7];
    const float* Wao = (const float*)d_in[8];
    const float* bao = (const float*)d_in[9];
    const float* W1  = (const float*)d_in[10];
    const float* b1  = (const float*)d_in[11];
    const float* Wo1 = (const float*)d_in[12];
    const float* bo1 = (const float*)d_in[13];
    const float* Wo2 = (const float*)d_in[14];
    const float* bo2 = (const float*)d_in[15];
    float* out = (float*)d_out;
    unsigned short* wsu = (unsigned short*)d_ws;

    unsigned short* bfw = wsu;
    unsigned short* kb  = wsu + KB_OFF;
    unsigned short* vtb = wsu + VTB_OFF;

    hipLaunchKernelGGL(k_prep, dim3(216), dim3(512), 0, stream,
                       temporal, bt, bin, Wt, Win, Ws, Wao, W1, Wo1,
                       kb, vtb, bfw);
    hipLaunchKernelGGL(k_main, dim3(256), dim3(512), 0, stream,
                       spatial, bs, bin, bfw, kb, vtb,
                       bao, b1, bo1, Wo2, bo2, out);
}